// Round 4
// baseline (32.983 us; speedup 1.0000x reference)
//
#include <hip/hip_runtime.h>

#define NBATCH   32
#define NCH      64
#define NNODE    4096
#define WW       97

// fp32 value of np.linspace(-1,1,4)[2] (and -[1])
#define XNEG 0.33333334f

typedef float f32x4 __attribute__((ext_vector_type(4)));

// Lagrange denominators in fp32 (match reference node values)
__host__ __device__ constexpr float lag_rd(int j) {
  constexpr float X1 = -XNEG, X2 = XNEG;
  constexpr float D0 = (-1.0f - X1) * (-1.0f - X2) * (-2.0f);
  constexpr float D1 = (X1 + 1.0f) * (X1 - X2) * (X1 - 1.0f);
  constexpr float D2 = (X2 + 1.0f) * (X2 - X1) * (X2 - 1.0f);
  constexpr float D3 = 2.0f * (1.0f - X1) * (1.0f - X2);
  return j == 0 ? 1.0f / D0 : j == 1 ? 1.0f / D1 : j == 2 ? 1.0f / D2 : 1.0f / D3;
}

// ---- Kernel A: expand + prescale the shared weight table into d_ws ----
// wexp[c*32 + id] = { w[c][3id+j] * RDj }   (64*32 float4 = 32 KB)
__global__ __launch_bounds__(512)
void pw_expand_kernel(const float* __restrict__ w, f32x4* __restrict__ wexp) {
  const int r = blockIdx.x * 512 + threadIdx.x;   // [0, 2048)
  const int c = r >> 5, i = r & 31;
  const float* wr = w + c * WW + 3 * i;
  f32x4 v;
  v[0] = wr[0] * lag_rd(0);
  v[1] = wr[1] * lag_rd(1);
  v[2] = wr[2] * lag_rd(2);
  v[3] = wr[3] * lag_rd(3);
  wexp[r] = v;
}

// ---- Kernel B: barrier-free main kernel (no LDS, no __syncthreads) ----
__global__ __launch_bounds__(512)
void pw_main_kernel(const float* __restrict__ x,
                    const f32x4* __restrict__ wexp,
                    float* __restrict__ out) {
  const int g   = blockIdx.x;
  const int b   = g >> 6;   // batch
  const int t   = g & 63;   // 64-wide nn block
  const int tid = threadIdx.x;

  const int l  = tid & 63;
  const int wv = tid >> 6;
  const int q  = l & 15;      // nn quad index
  const int cg = l >> 4;      // channel subgroup 0..3
  const int u0 = q << 2;

  // transposed source row x[b][t][*]; element (c, u) needs id of xrow[64u + c]
  const float* xrow = x + (((size_t)(b * NCH + t)) << 12);

  #pragma unroll
  for (int p = 0; p < 2; ++p) {
    const int c = cg + (wv << 2) + (p << 5);
    const size_t base = (((size_t)(b * NCH + c)) << 12) + ((size_t)(t << 6)) + u0;

    const f32x4 xq = *reinterpret_cast<const f32x4*>(x + base);

    // scattered transposed reads (L1/L2-hot; each row element read exactly once)
    float rv[4];
    #pragma unroll
    for (int i = 0; i < 4; ++i) rv[i] = xrow[((u0 + i) << 6) + c];

    f32x4 res;
    #pragma unroll
    for (int i = 0; i < 4; ++i) {
      // own bin id -> local coordinate (bitwise-identical to reference)
      const float xv = xq[i];
      const float tt = (xv + 1.0f) * 16.0f;
      int idm = (int)tt;
      idm = idm < 0 ? 0 : (idm > 31 ? 31 : idm);
      const float xmin = fmaf((float)idm, 0.0625f, -1.0f);
      const float xin  = fmaf(xv - xmin, 32.0f, -1.0f);

      // transposed element's bin id -> weight window (aligned dwordx4 gather)
      const float st = (rv[i] + 1.0f) * 16.0f;
      int idw = (int)st;
      idw = idw < 0 ? 0 : (idw > 31 ? 31 : idw);
      const f32x4 w4 = wexp[(c << 5) + idw];

      const float t0  = xin + 1.0f;
      const float t1  = xin + XNEG;
      const float t2  = xin - XNEG;
      const float t3  = xin - 1.0f;
      const float u01 = t0 * t1, u23 = t2 * t3;
      const float p0  = t1 * u23;
      const float p1  = t0 * u23;
      const float p2  = u01 * t3;
      const float p3  = u01 * t2;

      res[i] = fmaf(p3, w4[3], fmaf(p2, w4[2], fmaf(p1, w4[1], p0 * w4[0])));
    }
    __builtin_nontemporal_store(res, reinterpret_cast<f32x4*>(out + base));
  }
}

extern "C" void kernel_launch(void* const* d_in, const int* in_sizes, int n_in,
                              void* d_out, int out_size, void* d_ws, size_t ws_size,
                              hipStream_t stream) {
  const float* x = (const float*)d_in[0];
  const float* w = (const float*)d_in[1];
  float* out    = (float*)d_out;
  f32x4* wexp   = (f32x4*)d_ws;   // 32 KB scratch

  pw_expand_kernel<<<dim3(4), 512, 0, stream>>>(w, wexp);
  pw_main_kernel<<<dim3(NBATCH * (NNODE / 64)), 512, 0, stream>>>(x, wexp, out);
}

// Round 5
// 25.362 us; speedup vs baseline: 1.3005x; 1.3005x over previous
//
#include <hip/hip_runtime.h>

#define NBATCH   32
#define NCH      64
#define NNODE    4096
#define WW       97
#define NTHREADS 512
#define TILES    4

// fp32 value of np.linspace(-1,1,4)[2] (and -[1])
#define XNEG 0.33333334f

typedef float f32x4 __attribute__((ext_vector_type(4)));

__host__ __device__ constexpr float lag_rd(int j) {
  constexpr float X1 = -XNEG, X2 = XNEG;
  constexpr float D0 = (-1.0f - X1) * (-1.0f - X2) * (-2.0f);
  constexpr float D1 = (X1 + 1.0f) * (X1 - X2) * (X1 - 1.0f);
  constexpr float D2 = (X2 + 1.0f) * (X2 - X1) * (X2 - 1.0f);
  constexpr float D3 = 2.0f * (1.0f - X1) * (1.0f - X2);
  return j == 0 ? 1.0f / D0 : j == 1 ? 1.0f / D1 : j == 2 ? 1.0f / D2 : 1.0f / D3;
}

// ---- Kernel A: expand + prescale the shared weight table into d_ws ----
// wexp[c*32 + id] = { w[c][3id+j] * RDj }   (64*32 float4 = 32 KB)
__global__ __launch_bounds__(512)
void pw_expand_kernel(const float* __restrict__ w, f32x4* __restrict__ wexp) {
  const int r = blockIdx.x * 512 + threadIdx.x;   // [0, 2048)
  const int c = r >> 5, i = r & 31;
  const float* wr = w + c * WW + 3 * i;
  f32x4 v;
  v[0] = wr[0] * lag_rd(0);
  v[1] = wr[1] * lag_rd(1);
  v[2] = wr[2] * lag_rd(2);
  v[3] = wr[3] * lag_rd(3);
  wexp[r] = v;
}

// ---- Kernel B: 4 tiles per WG, software-pipelined row staging ----
__global__ __launch_bounds__(NTHREADS)
void pw_main_kernel(const float* __restrict__ x,
                    const f32x4* __restrict__ wexp_g,
                    float* __restrict__ out) {
  __shared__ f32x4 wexp[NCH * 32];                       // 32 KB
  __shared__ __align__(4) unsigned char sid[2][NCH * 68]; // 2 x 4.25 KB

  const int g   = blockIdx.x;
  const int b   = g >> 4;     // batch
  const int q   = g & 15;     // tile group: tiles 4q .. 4q+3
  const int tid = threadIdx.x;
  const int l   = tid & 63;
  const int wv  = tid >> 6;

  // ---- copy pre-scaled weight table to LDS (once per WG) ----
  #pragma unroll
  for (int k = 0; k < 4; ++k) {
    const int r = tid + k * NTHREADS;
    wexp[r] = wexp_g[r];
  }

  const float* slab = x + ((size_t)b << 18);   // x[b][0][0], 64*4096 floats

  // ---- stage ids for tile 0 ----
  {
    const float* row = slab + ((size_t)(q * TILES) << 12);
    #pragma unroll
    for (int k = 0; k < 2; ++k) {
      const int s4 = (tid + k * NTHREADS) << 2;
      const f32x4 xq = *reinterpret_cast<const f32x4*>(row + s4);
      const int u = s4 >> 6, cb = s4 & 63;
      #pragma unroll
      for (int i = 0; i < 4; ++i) {
        const float tt = (xq[i] + 1.0f) * 16.0f;
        int id = (int)tt;
        id = id < 0 ? 0 : (id > 31 ? 31 : id);
        sid[0][(cb + i) * 68 + u] = (unsigned char)id;
      }
    }
  }
  __syncthreads();

  const int cg = l >> 4;            // channel subgroup 0..3
  const int u0 = (l & 15) << 2;     // nn quad start

  #pragma unroll
  for (int j = 0; j < TILES; ++j) {
    const int t   = q * TILES + j;
    const int cur = j & 1;

    // issue next tile's row loads early (in flight under compute)
    f32x4 na, nb;
    if (j + 1 < TILES) {
      const float* nrow = slab + ((size_t)(t + 1) << 12);
      na = *reinterpret_cast<const f32x4*>(nrow + (tid << 2));
      nb = *reinterpret_cast<const f32x4*>(nrow + ((tid + NTHREADS) << 2));
    }

    // ---- compute tile t ----
    #pragma unroll
    for (int p = 0; p < 2; ++p) {
      const int c = cg + (wv << 2) + (p << 5);
      const size_t base = (((size_t)(b * NCH + c)) << 12) + ((size_t)(t << 6)) + u0;

      const f32x4 xq = *reinterpret_cast<const f32x4*>(x + base);
      const unsigned int ids4 =
          *reinterpret_cast<const unsigned int*>(&sid[cur][c * 68 + u0]);

      f32x4 res;
      #pragma unroll
      for (int i = 0; i < 4; ++i) {
        const float xv = xq[i];
        const float tt = (xv + 1.0f) * 16.0f;
        int idm = (int)tt;
        idm = idm < 0 ? 0 : (idm > 31 ? 31 : idm);
        const float xmin = fmaf((float)idm, 0.0625f, -1.0f);
        const float xin  = fmaf(xv - xmin, 32.0f, -1.0f);

        const int idw  = (ids4 >> (8 * i)) & 0xff;
        const f32x4 w4 = wexp[(c << 5) + idw];

        const float t0  = xin + 1.0f;
        const float t1  = xin + XNEG;
        const float t2  = xin - XNEG;
        const float t3  = xin - 1.0f;
        const float u01 = t0 * t1, u23 = t2 * t3;
        const float p0  = t1 * u23;
        const float p1  = t0 * u23;
        const float p2  = u01 * t3;
        const float p3  = u01 * t2;

        res[i] = fmaf(p3, w4[3], fmaf(p2, w4[2], fmaf(p1, w4[1], p0 * w4[0])));
      }
      __builtin_nontemporal_store(res, reinterpret_cast<f32x4*>(out + base));
    }

    // ---- write next tile's ids to the alternate buffer, then barrier ----
    if (j + 1 < TILES) {
      #pragma unroll
      for (int k = 0; k < 2; ++k) {
        const f32x4 xq = (k == 0) ? na : nb;
        const int s4 = (tid + k * NTHREADS) << 2;
        const int u = s4 >> 6, cb = s4 & 63;
        #pragma unroll
        for (int i = 0; i < 4; ++i) {
          const float tt = (xq[i] + 1.0f) * 16.0f;
          int id = (int)tt;
          id = id < 0 ? 0 : (id > 31 ? 31 : id);
          sid[cur ^ 1][(cb + i) * 68 + u] = (unsigned char)id;
        }
      }
      __syncthreads();
    }
  }
}

extern "C" void kernel_launch(void* const* d_in, const int* in_sizes, int n_in,
                              void* d_out, int out_size, void* d_ws, size_t ws_size,
                              hipStream_t stream) {
  const float* x = (const float*)d_in[0];
  const float* w = (const float*)d_in[1];
  float* out    = (float*)d_out;
  f32x4* wexp   = (f32x4*)d_ws;   // 32 KB scratch

  pw_expand_kernel<<<dim3(4), 512, 0, stream>>>(w, wexp);
  pw_main_kernel<<<dim3(NBATCH * (NNODE / 64) / TILES), NTHREADS, 0, stream>>>(x, wexp, out);
}